// Round 10
// baseline (298.964 us; speedup 1.0000x reference)
//
#include <hip/hip_runtime.h>
#include <hip/hip_bf16.h>

constexpr int BATCH = 32768;
constexpr int KDIM  = 128;    // IN_F
constexpr int NDIM  = 2048;   // OUT_F

using f32x4  = __attribute__((ext_vector_type(4))) float;
using bf16x8 = __attribute__((ext_vector_type(8))) short;

// ---------------------------------------------------------------------------
// Fragment order for mfma_f32_16x16x32_bf16 (verified R2/R3):
//   A (MxK): lane l holds m = l&15,  k(j) = 4*(l>>4) + (j&3) + 16*(j>>2)
//   B (KxN): lane l holds n = l&15,  same k(j)
//   D:       lane l holds col = l&15, row = (l>>4)*4 + reg
// 2-term split: z = (x_hi + x_lo) @ W_hi  (absmax ~8e-3 < 2e-2 threshold)
//
// R9 (swapped operands): mfma(W_frag, x_frag) = z^T -> lane owns (row, 4 cols),
// pm/out are per-lane aligned f32x4, no LDS transpose. R9 lesson: still 3.3x
// over the 67us memory floor because HBM sits idle during GEMM + Michelot
// phases (VGPR=56 -> no pm prefetch in flight). R10: software-pipeline the pm
// loads into the GEMM t-loop (8 slots, ~640cy cover) and fold the Michelot
// iteration to ONE barrier (__syncthreads_and doubles as publish barrier).
// ---------------------------------------------------------------------------

__device__ inline void split_bf16(float v, ushort& hi, ushort& lo) {
    __hip_bfloat16 h = __float2bfloat16(v);
    float r = v - __bfloat162float(h);
    __hip_bfloat16 l = __float2bfloat16(r);
    hi = *reinterpret_cast<ushort*>(&h);
    lo = *reinterpret_cast<ushort*>(&l);
}

// W [128][2048] -> Bh[nt=128][kk=4][lane=64][j=8]  (hi only)
__global__ __launch_bounds__(256)
void conv_w_kernel(const float* __restrict__ W, ushort* __restrict__ Bh) {
    int id = blockIdx.x * 256 + threadIdx.x;      // 0 .. 262143
    int j  = id & 7;
    int l  = (id >> 3) & 63;
    int kk = (id >> 9) & 3;
    int nt = id >> 11;
    int k  = kk * 32 + 4 * (l >> 4) + (j & 3) + 16 * (j >> 2);
    int n  = nt * 16 + (l & 15);
    __hip_bfloat16 h = __float2bfloat16(W[k * NDIM + n]);
    Bh[id] = *reinterpret_cast<ushort*>(&h);
}

// x [32768][128] -> A{h,l}[rt=2048][kk=4][lane=64][j=8]
__global__ __launch_bounds__(256)
void conv_x_kernel(const float* __restrict__ x,
                   ushort* __restrict__ Ah, ushort* __restrict__ Al) {
    int id = blockIdx.x * 256 + threadIdx.x;      // 0 .. 4194303
    int j  = id & 7;
    int l  = (id >> 3) & 63;
    int kk = (id >> 9) & 3;
    int rt = id >> 11;
    int k  = kk * 32 + 4 * (l >> 4) + (j & 3) + 16 * (j >> 2);
    int m  = rt * 16 + (l & 15);
    ushort hi, lo;
    split_bf16(x[m * KDIM + k], hi, lo);
    Ah[id] = hi; Al[id] = lo;
}

// ---------------------------------------------------------------------------
// Main: grid 2048, 512 thr (8 waves), 16 rows x 2048 cols per block.
// Wave q: col tiles q*16..q*16+15 (swapped-operand MFMA, acc[16] f32x4).
// Lane l owns row l&15, cols {q*256 + t*16 + (l>>4)*4 + r}.
// pm loads pipelined into the GEMM (8 f32x4 slots); gate fused per-t.
// Michelot: 1 barrier/iter (__syncthreads_and with lagged convergence).
// ---------------------------------------------------------------------------
constexpr int GRID = BATCH / 16;                // 2048

__global__ __launch_bounds__(512)
void mfma_sparsemax_swapped(const ushort* __restrict__ Ah, const ushort* __restrict__ Al,
                            const ushort* __restrict__ Bh,
                            const float* __restrict__ pm, float* __restrict__ out) {
    __shared__ float2 red[2][8][16];            // [buf][wave][row], 2 KB

    const int tid = threadIdx.x;
    const int l   = tid & 63;
    const int q   = tid >> 6;                   // wave id 0..7
    const int g   = l >> 4;
    const int m0  = l & 15;                     // my batch row (local)
    const int rt  = blockIdx.x;
    const long grow = (long)rt * 16 + m0;       // my batch row (global)

    const bf16x8* A8h = reinterpret_cast<const bf16x8*>(Ah);
    const bf16x8* A8l = reinterpret_cast<const bf16x8*>(Al);
    const bf16x8* B8h = reinterpret_cast<const bf16x8*>(Bh);

    // ---- pm pipeline: issue first 8 slots before anything else ----
    const float* pmbase = pm + grow * NDIM + q * 256 + g * 4;
    f32x4 pmv[8];
    #pragma unroll
    for (int j = 0; j < 8; ++j)
        pmv[j] = *reinterpret_cast<const f32x4*>(pmbase + j * 16);

    // ---- x fragments (16 rows of this tile) ----
    bf16x8 ah[4], al4[4];
    #pragma unroll
    for (int kk = 0; kk < 4; ++kk) {
        ah[kk]  = A8h[(rt * 4 + kk) * 64 + l];
        al4[kk] = A8l[(rt * 4 + kk) * 64 + l];
    }

    // ---- GEMM, swapped operands; gate fused; refill pm slot for t+8 ----
    f32x4 acc[16];
    #pragma unroll
    for (int t = 0; t < 16; ++t) {
        const int nt = q * 16 + t;
        f32x4 c = {0.f, 0.f, 0.f, 0.f};
        #pragma unroll
        for (int kk = 0; kk < 4; ++kk) {
            bf16x8 b = B8h[(nt * 4 + kk) * 64 + l];
            c = __builtin_amdgcn_mfma_f32_16x16x32_bf16(b, ah[kk],  c, 0, 0, 0);
            c = __builtin_amdgcn_mfma_f32_16x16x32_bf16(b, al4[kk], c, 0, 0, 0);
        }
        c *= pmv[t & 7];                        // gate: acc[t] final here
        acc[t] = c;
        if (t < 8)                              // refill slot t with load for t+8
            pmv[t] = *reinterpret_cast<const f32x4*>(pmbase + (t + 8) * 16);
    }

    // ---- init: row max & sum ----
    float mx = acc[0][0], sm = 0.f;
    #pragma unroll
    for (int t = 0; t < 16; ++t)
        #pragma unroll
        for (int r = 0; r < 4; ++r) { float v = acc[t][r]; mx = fmaxf(mx, v); sm += v; }
    mx = fmaxf(mx, __shfl_xor(mx, 16, 64));
    mx = fmaxf(mx, __shfl_xor(mx, 32, 64));
    sm += __shfl_xor(sm, 16, 64);
    sm += __shfl_xor(sm, 32, 64);
    if (l < 16) red[0][q][l] = make_float2(mx, sm);
    __syncthreads();
    float M = -1e30f, S = 0.f;
    #pragma unroll
    for (int w = 0; w < 8; ++w) { float2 e = red[0][w][m0]; M = fmaxf(M, e.x); S += e.y; }
    float tau = fmaxf(M - 1.f, (S - 1.f) * (1.f / 2048.f));
    float cprev = -1.f;
    bool  done  = false;

    // ---- Michelot fixed-point: ONE barrier per iteration ----
    for (int it = 0; it < 32; ++it) {
        float ps = 0.f, pc = 0.f;
        #pragma unroll
        for (int t = 0; t < 16; ++t)
            #pragma unroll
            for (int r = 0; r < 4; ++r) {
                float v = acc[t][r];
                bool a = v > tau;
                ps += a ? v : 0.f;
                pc += a ? 1.f : 0.f;
            }
        ps += __shfl_xor(ps, 16, 64);
        ps += __shfl_xor(ps, 32, 64);
        pc += __shfl_xor(pc, 16, 64);
        pc += __shfl_xor(pc, 32, 64);
        const int buf = (it + 1) & 1;           // it0 -> buf1 (init used buf0)
        if (l < 16) red[buf][q][l] = make_float2(ps, pc);
        // barrier publishes red AND aggregates lagged convergence flag
        if (__syncthreads_and(done)) break;     // tau already at fixpoint
        float SS = 0.f, CC = 0.f;
        #pragma unroll
        for (int w = 0; w < 8; ++w) { float2 e = red[buf][w][m0]; SS += e.x; CC += e.y; }
        tau = (SS - 1.f) / CC;                  // CC >= 1 always
        done = (CC == cprev);                   // nested sets + equal count = fixpoint
        cprev = CC;
    }

    // ---- out = max(z - tau, 0): per-lane aligned f32x4 stores ----
    float* obase = out + grow * NDIM + q * 256 + g * 4;
    #pragma unroll
    for (int t = 0; t < 16; ++t) {
        f32x4 v = acc[t];
        f32x4 o;
        o.x = fmaxf(v.x - tau, 0.f);
        o.y = fmaxf(v.y - tau, 0.f);
        o.z = fmaxf(v.z - tau, 0.f);
        o.w = fmaxf(v.w - tau, 0.f);
        *reinterpret_cast<f32x4*>(obase + t * 16) = o;
    }
}

// ---------------------------------------------------------------------------
// Fallback (R1 kernel) if d_ws too small.
// ---------------------------------------------------------------------------
__device__ inline float wave_sum(float v) {
    #pragma unroll
    for (int off = 32; off > 0; off >>= 1) v += __shfl_xor(v, off, 64);
    return v;
}

__global__ __launch_bounds__(256)
void fused_sparsemax_fallback(const float* __restrict__ x,
                              const float* __restrict__ pm,
                              const float* __restrict__ W,
                              float* __restrict__ out) {
    __shared__ float xs[8][KDIM];
    __shared__ float zsf[4][NDIM];
    const int tid  = threadIdx.x;
    const int lane = tid & 63;
    const int wv   = tid >> 6;
    const long r0  = (long)blockIdx.x * 8;
    {
        const float4* src = reinterpret_cast<const float4*>(x + r0 * KDIM);
        reinterpret_cast<float4*>(&xs[0][0])[tid] = src[tid];
    }
    __syncthreads();
    float acc[8][8];
    #pragma unroll
    for (int r = 0; r < 8; ++r)
        #pragma unroll
        for (int j = 0; j < 8; ++j) acc[r][j] = 0.f;
    const float4* Wv4 = reinterpret_cast<const float4*>(W);
    #pragma unroll 4
    for (int k = 0; k < KDIM; ++k) {
        const float4 w0 = Wv4[k * (NDIM / 4) + tid];
        const float4 w1 = Wv4[k * (NDIM / 4) + 256 + tid];
        #pragma unroll
        for (int r = 0; r < 8; ++r) {
            const float xv = xs[r][k];
            acc[r][0] = fmaf(xv, w0.x, acc[r][0]);
            acc[r][1] = fmaf(xv, w0.y, acc[r][1]);
            acc[r][2] = fmaf(xv, w0.z, acc[r][2]);
            acc[r][3] = fmaf(xv, w0.w, acc[r][3]);
            acc[r][4] = fmaf(xv, w1.x, acc[r][4]);
            acc[r][5] = fmaf(xv, w1.y, acc[r][5]);
            acc[r][6] = fmaf(xv, w1.z, acc[r][6]);
            acc[r][7] = fmaf(xv, w1.w, acc[r][7]);
        }
    }
    const float4* pmv = reinterpret_cast<const float4*>(pm);
    #pragma unroll
    for (int half = 0; half < 2; ++half) {
        __syncthreads();
        #pragma unroll
        for (int rr = 0; rr < 4; ++rr) {
            const int r = half * 4 + rr;
            const long rowbase4 = (r0 + r) * (NDIM / 4);
            const float4 m0 = pmv[rowbase4 + tid];
            const float4 m1 = pmv[rowbase4 + 256 + tid];
            float4 z0, z1;
            z0.x = acc[r][0] * m0.x; z0.y = acc[r][1] * m0.y;
            z0.z = acc[r][2] * m0.z; z0.w = acc[r][3] * m0.w;
            z1.x = acc[r][4] * m1.x; z1.y = acc[r][5] * m1.y;
            z1.z = acc[r][6] * m1.z; z1.w = acc[r][7] * m1.w;
            float4* zr = reinterpret_cast<float4*>(&zsf[rr][0]);
            zr[tid] = z0; zr[256 + tid] = z1;
        }
        __syncthreads();
        float zvv[32];
        const float4* zr = reinterpret_cast<const float4*>(&zsf[wv][0]);
        #pragma unroll
        for (int cc = 0; cc < 8; ++cc) {
            const float4 v = zr[cc * 64 + lane];
            zvv[cc * 4 + 0] = v.x; zvv[cc * 4 + 1] = v.y;
            zvv[cc * 4 + 2] = v.z; zvv[cc * 4 + 3] = v.w;
        }
        float s = 0.f;
        #pragma unroll
        for (int i = 0; i < 32; ++i) s += zvv[i];
        s = wave_sum(s);
        float tau = (s - 1.f) / 2048.f;
        float cprev = 2048.f;
        for (int itf = 0; itf < 64; ++itf) {
            float ps = 0.f, pc = 0.f;
            #pragma unroll
            for (int i = 0; i < 32; ++i)
                if (zvv[i] > tau) { ps += zvv[i]; pc += 1.f; }
            ps = wave_sum(ps);
            pc = wave_sum(pc);
            tau = (ps - 1.f) / pc;
            if (pc == cprev) break;
            cprev = pc;
        }
        float4* orow = reinterpret_cast<float4*>(out + (r0 + half * 4 + wv) * NDIM);
        #pragma unroll
        for (int cc = 0; cc < 8; ++cc) {
            float4 v;
            v.x = fmaxf(zvv[cc * 4 + 0] - tau, 0.f);
            v.y = fmaxf(zvv[cc * 4 + 1] - tau, 0.f);
            v.z = fmaxf(zvv[cc * 4 + 2] - tau, 0.f);
            v.w = fmaxf(zvv[cc * 4 + 3] - tau, 0.f);
            orow[cc * 64 + lane] = v;
        }
    }
}

extern "C" void kernel_launch(void* const* d_in, const int* in_sizes, int n_in,
                              void* d_out, int out_size, void* d_ws, size_t ws_size,
                              hipStream_t stream) {
    const float* x  = (const float*)d_in[0];   // [32768, 128]
    const float* pm = (const float*)d_in[1];   // [32768, 2048]
    const float* W  = (const float*)d_in[2];   // [128, 2048]
    float* out = (float*)d_out;

    const size_t szA = (size_t)BATCH * KDIM * sizeof(ushort);   // 8 MB each
    const size_t szB = (size_t)KDIM * NDIM * sizeof(ushort);    // 512 KB
    const size_t need = 2 * szA + szB;

    if (ws_size >= need) {
        char* base = (char*)d_ws;
        ushort* Ah = (ushort*)(base);
        ushort* Al = (ushort*)(base + szA);
        ushort* Bh = (ushort*)(base + 2 * szA);

        conv_x_kernel<<<(BATCH * KDIM) / 256, 256, 0, stream>>>(x, Ah, Al);
        conv_w_kernel<<<(KDIM * NDIM) / 256, 256, 0, stream>>>(W, Bh);
        mfma_sparsemax_swapped<<<GRID, 512, 0, stream>>>(Ah, Al, Bh, pm, out);
    } else {
        fused_sparsemax_fallback<<<BATCH / 8, 256, 0, stream>>>(x, pm, W, out);
    }
}

// Round 12
// 225.030 us; speedup vs baseline: 1.3286x; 1.3286x over previous
//
#include <hip/hip_runtime.h>
#include <hip/hip_bf16.h>

constexpr int BATCH = 32768;
constexpr int KDIM  = 128;    // IN_F
constexpr int NDIM  = 2048;   // OUT_F

using f32x4  = __attribute__((ext_vector_type(4))) float;
using bf16x8 = __attribute__((ext_vector_type(8))) short;

// ---------------------------------------------------------------------------
// Fragment order for mfma_f32_16x16x32_bf16 (verified R2/R3):
//   A (MxK): lane l holds m = l&15,  k(j) = 4*(l>>4) + (j&3) + 16*(j>>2)
//   B (KxN): lane l holds n = l&15,  same k(j)
//   D:       lane l holds col = l&15, row = (l>>4)*4 + reg
// 2-term split: z = (x_hi + x_lo) @ W_hi  (absmax ~8e-3 < 2e-2 threshold)
//
// R9 swapped operands: mfma(W_frag, x_frag) = z^T -> lane owns (row, 4 cols).
// R10 lesson: __launch_bounds__(512,4) is load-bearing (else 1 block/CU).
// R11 lesson (correctness): the wave-local solver for row 2q+sub must seed
// with THAT row's tau0, not the thread's own-row tau0 -> stage tau0[16] in
// LDS. Michelot from tau0[row]: active set subset of C={v>tau0[row]}, solver
// is shuffle-only on <=128 candidates, zero barriers in the loop.
// ---------------------------------------------------------------------------

__device__ inline void split_bf16(float v, ushort& hi, ushort& lo) {
    __hip_bfloat16 h = __float2bfloat16(v);
    float r = v - __bfloat162float(h);
    __hip_bfloat16 l = __float2bfloat16(r);
    hi = *reinterpret_cast<ushort*>(&h);
    lo = *reinterpret_cast<ushort*>(&l);
}

// W [128][2048] -> Bh[nt=128][kk=4][lane=64][j=8]  (hi only)
__global__ __launch_bounds__(256)
void conv_w_kernel(const float* __restrict__ W, ushort* __restrict__ Bh) {
    int id = blockIdx.x * 256 + threadIdx.x;      // 0 .. 262143
    int j  = id & 7;
    int l  = (id >> 3) & 63;
    int kk = (id >> 9) & 3;
    int nt = id >> 11;
    int k  = kk * 32 + 4 * (l >> 4) + (j & 3) + 16 * (j >> 2);
    int n  = nt * 16 + (l & 15);
    __hip_bfloat16 h = __float2bfloat16(W[k * NDIM + n]);
    Bh[id] = *reinterpret_cast<ushort*>(&h);
}

// x [32768][128] -> A{h,l}[rt=2048][kk=4][lane=64][j=8]
__global__ __launch_bounds__(256)
void conv_x_kernel(const float* __restrict__ x,
                   ushort* __restrict__ Ah, ushort* __restrict__ Al) {
    int id = blockIdx.x * 256 + threadIdx.x;      // 0 .. 4194303
    int j  = id & 7;
    int l  = (id >> 3) & 63;
    int kk = (id >> 9) & 3;
    int rt = id >> 11;
    int k  = kk * 32 + 4 * (l >> 4) + (j & 3) + 16 * (j >> 2);
    int m  = rt * 16 + (l & 15);
    ushort hi, lo;
    split_bf16(x[m * KDIM + k], hi, lo);
    Ah[id] = hi; Al[id] = lo;
}

// ---------------------------------------------------------------------------
// Main: grid 2048, 512 thr (8 waves), 16 rows x 2048 cols per block.
// Wave q: col tiles q*16..q*16+15 (swapped MFMA, acc[16] f32x4 in AGPRs).
// Lane l owns row l&15, cols {q*256 + t*16 + (l>>4)*4 + r}.
// ---------------------------------------------------------------------------
constexpr int GRID = BATCH / 16;                // 2048
constexpr int CAP  = 128;                       // candidates per row (4/lane/half-wave)

__global__ __launch_bounds__(512, 4)
void mfma_sparsemax_swapped(const ushort* __restrict__ Ah, const ushort* __restrict__ Al,
                            const ushort* __restrict__ Bh,
                            const float* __restrict__ pm, float* __restrict__ out) {
    __shared__ float2 red[2][8][16];            // init + fallback combine, 2 KB
    __shared__ float  cand[16][CAP];            // 8 KB
    __shared__ int    cnt[16];
    __shared__ float  taus0[16];                // per-row tau0 (solver seeds)
    __shared__ float  taus[16];                 // per-row final tau

    const int tid = threadIdx.x;
    const int l   = tid & 63;
    const int q   = tid >> 6;                   // wave id 0..7
    const int g   = l >> 4;
    const int m0  = l & 15;                     // my batch row (local)
    const int rt  = blockIdx.x;
    const long grow = (long)rt * 16 + m0;       // my batch row (global)

    const bf16x8* A8h = reinterpret_cast<const bf16x8*>(Ah);
    const bf16x8* A8l = reinterpret_cast<const bf16x8*>(Al);
    const bf16x8* B8h = reinterpret_cast<const bf16x8*>(Bh);

    // ---- x fragments (16 rows of this tile) ----
    bf16x8 ah[4], al4[4];
    #pragma unroll
    for (int kk = 0; kk < 4; ++kk) {
        ah[kk]  = A8h[(rt * 4 + kk) * 64 + l];
        al4[kk] = A8l[(rt * 4 + kk) * 64 + l];
    }

    // ---- GEMM, swapped operands: acc[t] = z[grow][q*256 + t*16 + g*4 .. +3]
    f32x4 acc[16];
    #pragma unroll
    for (int t = 0; t < 16; ++t) {
        const int nt = q * 16 + t;
        f32x4 c = {0.f, 0.f, 0.f, 0.f};
        #pragma unroll
        for (int kk = 0; kk < 4; ++kk) {
            bf16x8 b = B8h[(nt * 4 + kk) * 64 + l];
            c = __builtin_amdgcn_mfma_f32_16x16x32_bf16(b, ah[kk],  c, 0, 0, 0);
            c = __builtin_amdgcn_mfma_f32_16x16x32_bf16(b, al4[kk], c, 0, 0, 0);
        }
        acc[t] = c;
    }

    // ---- gate by prev_mask: per-lane aligned f32x4 ----
    const float* pmbase = pm + grow * NDIM + q * 256 + g * 4;
    #pragma unroll
    for (int t = 0; t < 16; ++t) {
        f32x4 p = *reinterpret_cast<const f32x4*>(pmbase + t * 16);
        acc[t] *= p;
    }

    // ---- init: row max & sum -> tau0 (per row) ----
    float mx = acc[0][0], sm = 0.f;
    #pragma unroll
    for (int t = 0; t < 16; ++t)
        #pragma unroll
        for (int r = 0; r < 4; ++r) { float v = acc[t][r]; mx = fmaxf(mx, v); sm += v; }
    mx = fmaxf(mx, __shfl_xor(mx, 16, 64));
    mx = fmaxf(mx, __shfl_xor(mx, 32, 64));
    sm += __shfl_xor(sm, 16, 64);
    sm += __shfl_xor(sm, 32, 64);
    if (l < 16) red[0][q][l] = make_float2(mx, sm);
    if (tid < 16) cnt[tid] = 0;
    __syncthreads();                                            // [1]
    float M = -1e30f, S = 0.f;
    #pragma unroll
    for (int w = 0; w < 8; ++w) { float2 e = red[0][w][m0]; M = fmaxf(M, e.x); S += e.y; }
    const float tau0 = fmaxf(M - 1.f, (S - 1.f) * (1.f / 2048.f));
    if (tid < 16) taus0[tid] = tau0;            // tid<16 -> m0 == tid

    // ---- push candidates (v > tau0, own row) into per-row LDS lists ----
    #pragma unroll
    for (int t = 0; t < 16; ++t)
        #pragma unroll
        for (int r = 0; r < 4; ++r) {
            float v = acc[t][r];
            if (v > tau0) {
                int idx = atomicAdd(&cnt[m0], 1);
                if (idx < CAP) cand[m0][idx] = v;
            }
        }
    __syncthreads();                                            // [2]
    const bool ovf = __syncthreads_or((tid < 16) && (cnt[tid] > CAP));  // [3]

    if (!ovf) {
        // ---- wave-local Michelot: half-wave (q,sub) owns row 2q+sub ----
        const int sub    = l >> 5;              // half-wave id
        const int lane32 = l & 31;
        const int row    = 2 * q + sub;
        const int n      = cnt[row];
        const float t0r  = taus0[row];          // THIS row's seed (R11 bugfix)
        float cv[4];
        #pragma unroll
        for (int j = 0; j < 4; ++j) {
            int idx = lane32 + 32 * j;
            cv[j] = (idx < n) ? cand[row][idx] : -1e30f;
        }
        float tau = t0r, cprev = -1.f;
        for (int it = 0; it < 64; ++it) {
            float ps = 0.f, pc = 0.f;
            #pragma unroll
            for (int j = 0; j < 4; ++j) {
                bool a = cv[j] > tau;
                ps += a ? cv[j] : 0.f;
                pc += a ? 1.f : 0.f;
            }
            #pragma unroll
            for (int off = 1; off < 32; off <<= 1) {            // within half-wave
                ps += __shfl_xor(ps, off, 64);
                pc += __shfl_xor(pc, off, 64);
            }
            tau = (ps - 1.f) / pc;              // pc >= 1 (rowmax in candidates)
            bool done = (pc == cprev);          // stable count = fixpoint
            cprev = pc;
            if (__all(done)) break;             // converged halves idempotent
        }
        if (lane32 == 0) taus[row] = tau;
    } else {
        // ---- fallback: block-wide Michelot (degenerate rows), R9 structure ----
        float tau = tau0, cprev = -1.f;
        for (int it = 0; it < 32; ++it) {
            float ps = 0.f, pc = 0.f;
            #pragma unroll
            for (int t = 0; t < 16; ++t)
                #pragma unroll
                for (int r = 0; r < 4; ++r) {
                    float v = acc[t][r];
                    bool a = v > tau;
                    ps += a ? v : 0.f;
                    pc += a ? 1.f : 0.f;
                }
            ps += __shfl_xor(ps, 16, 64);
            ps += __shfl_xor(ps, 32, 64);
            pc += __shfl_xor(pc, 16, 64);
            pc += __shfl_xor(pc, 32, 64);
            const int buf = (it + 1) & 1;
            if (l < 16) red[buf][q][l] = make_float2(ps, pc);
            __syncthreads();
            float SS = 0.f, CC = 0.f;
            #pragma unroll
            for (int w = 0; w < 8; ++w) { float2 e = red[buf][w][m0]; SS += e.x; CC += e.y; }
            tau = (SS - 1.f) / CC;
            int done = (CC == cprev);
            cprev = CC;
            if (__syncthreads_and(done)) break;
        }
        if (tid < 16) taus[m0] = tau;           // tid<16 -> m0 == tid
    }
    __syncthreads();                                            // [4]
    const float mytau = taus[m0];

    // ---- out = max(z - tau, 0): per-lane aligned f32x4 stores ----
    float* obase = out + grow * NDIM + q * 256 + g * 4;
    #pragma unroll
    for (int t = 0; t < 16; ++t) {
        f32x4 v = acc[t];
        f32x4 o;
        o.x = fmaxf(v.x - mytau, 0.f);
        o.y = fmaxf(v.y - mytau, 0.f);
        o.z = fmaxf(v.z - mytau, 0.f);
        o.w = fmaxf(v.w - mytau, 0.f);
        *reinterpret_cast<f32x4*>(obase + t * 16) = o;
    }
}

// ---------------------------------------------------------------------------
// Fallback (R1 kernel) if d_ws too small.
// ---------------------------------------------------------------------------
__device__ inline float wave_sum(float v) {
    #pragma unroll
    for (int off = 32; off > 0; off >>= 1) v += __shfl_xor(v, off, 64);
    return v;
}

__global__ __launch_bounds__(256)
void fused_sparsemax_fallback(const float* __restrict__ x,
                              const float* __restrict__ pm,
                              const float* __restrict__ W,
                              float* __restrict__ out) {
    __shared__ float xs[8][KDIM];
    __shared__ float zsf[4][NDIM];
    const int tid  = threadIdx.x;
    const int lane = tid & 63;
    const int wv   = tid >> 6;
    const long r0  = (long)blockIdx.x * 8;
    {
        const float4* src = reinterpret_cast<const float4*>(x + r0 * KDIM);
        reinterpret_cast<float4*>(&xs[0][0])[tid] = src[tid];
    }
    __syncthreads();
    float acc[8][8];
    #pragma unroll
    for (int r = 0; r < 8; ++r)
        #pragma unroll
        for (int j = 0; j < 8; ++j) acc[r][j] = 0.f;
    const float4* Wv4 = reinterpret_cast<const float4*>(W);
    #pragma unroll 4
    for (int k = 0; k < KDIM; ++k) {
        const float4 w0 = Wv4[k * (NDIM / 4) + tid];
        const float4 w1 = Wv4[k * (NDIM / 4) + 256 + tid];
        #pragma unroll
        for (int r = 0; r < 8; ++r) {
            const float xv = xs[r][k];
            acc[r][0] = fmaf(xv, w0.x, acc[r][0]);
            acc[r][1] = fmaf(xv, w0.y, acc[r][1]);
            acc[r][2] = fmaf(xv, w0.z, acc[r][2]);
            acc[r][3] = fmaf(xv, w0.w, acc[r][3]);
            acc[r][4] = fmaf(xv, w1.x, acc[r][4]);
            acc[r][5] = fmaf(xv, w1.y, acc[r][5]);
            acc[r][6] = fmaf(xv, w1.z, acc[r][6]);
            acc[r][7] = fmaf(xv, w1.w, acc[r][7]);
        }
    }
    const float4* pmv = reinterpret_cast<const float4*>(pm);
    #pragma unroll
    for (int half = 0; half < 2; ++half) {
        __syncthreads();
        #pragma unroll
        for (int rr = 0; rr < 4; ++rr) {
            const int r = half * 4 + rr;
            const long rowbase4 = (r0 + r) * (NDIM / 4);
            const float4 m0 = pmv[rowbase4 + tid];
            const float4 m1 = pmv[rowbase4 + 256 + tid];
            float4 z0, z1;
            z0.x = acc[r][0] * m0.x; z0.y = acc[r][1] * m0.y;
            z0.z = acc[r][2] * m0.z; z0.w = acc[r][3] * m0.w;
            z1.x = acc[r][4] * m1.x; z1.y = acc[r][5] * m1.y;
            z1.z = acc[r][6] * m1.z; z1.w = acc[r][7] * m1.w;
            float4* zr = reinterpret_cast<float4*>(&zsf[rr][0]);
            zr[tid] = z0; zr[256 + tid] = z1;
        }
        __syncthreads();
        float zvv[32];
        const float4* zr = reinterpret_cast<const float4*>(&zsf[wv][0]);
        #pragma unroll
        for (int cc = 0; cc < 8; ++cc) {
            const float4 v = zr[cc * 64 + lane];
            zvv[cc * 4 + 0] = v.x; zvv[cc * 4 + 1] = v.y;
            zvv[cc * 4 + 2] = v.z; zvv[cc * 4 + 3] = v.w;
        }
        float s = 0.f;
        #pragma unroll
        for (int i = 0; i < 32; ++i) s += zvv[i];
        s = wave_sum(s);
        float tau = (s - 1.f) / 2048.f;
        float cprev = 2048.f;
        for (int itf = 0; itf < 64; ++itf) {
            float ps = 0.f, pc = 0.f;
            #pragma unroll
            for (int i = 0; i < 32; ++i)
                if (zvv[i] > tau) { ps += zvv[i]; pc += 1.f; }
            ps = wave_sum(ps);
            pc = wave_sum(pc);
            tau = (ps - 1.f) / pc;
            if (pc == cprev) break;
            cprev = pc;
        }
        float4* orow = reinterpret_cast<float4*>(out + (r0 + half * 4 + wv) * NDIM);
        #pragma unroll
        for (int cc = 0; cc < 8; ++cc) {
            float4 v;
            v.x = fmaxf(zvv[cc * 4 + 0] - tau, 0.f);
            v.y = fmaxf(zvv[cc * 4 + 1] - tau, 0.f);
            v.z = fmaxf(zvv[cc * 4 + 2] - tau, 0.f);
            v.w = fmaxf(zvv[cc * 4 + 3] - tau, 0.f);
            orow[cc * 64 + lane] = v;
        }
    }
}

extern "C" void kernel_launch(void* const* d_in, const int* in_sizes, int n_in,
                              void* d_out, int out_size, void* d_ws, size_t ws_size,
                              hipStream_t stream) {
    const float* x  = (const float*)d_in[0];   // [32768, 128]
    const float* pm = (const float*)d_in[1];   // [32768, 2048]
    const float* W  = (const float*)d_in[2];   // [128, 2048]
    float* out = (float*)d_out;

    const size_t szA = (size_t)BATCH * KDIM * sizeof(ushort);   // 8 MB each
    const size_t szB = (size_t)KDIM * NDIM * sizeof(ushort);    // 512 KB
    const size_t need = 2 * szA + szB;

    if (ws_size >= need) {
        char* base = (char*)d_ws;
        ushort* Ah = (ushort*)(base);
        ushort* Al = (ushort*)(base + szA);
        ushort* Bh = (ushort*)(base + 2 * szA);

        conv_x_kernel<<<(BATCH * KDIM) / 256, 256, 0, stream>>>(x, Ah, Al);
        conv_w_kernel<<<(KDIM * NDIM) / 256, 256, 0, stream>>>(W, Bh);
        mfma_sparsemax_swapped<<<GRID, 512, 0, stream>>>(Ah, Al, Bh, pm, out);
    } else {
        fused_sparsemax_fallback<<<BATCH / 8, 256, 0, stream>>>(x, pm, W, out);
    }
}

// Round 13
// 220.665 us; speedup vs baseline: 1.3548x; 1.0198x over previous
//
#include <hip/hip_runtime.h>
#include <hip/hip_bf16.h>

constexpr int BATCH = 32768;
constexpr int KDIM  = 128;    // IN_F
constexpr int NDIM  = 2048;   // OUT_F

using f32x4  = __attribute__((ext_vector_type(4))) float;
using bf16x8 = __attribute__((ext_vector_type(8))) short;

// ---------------------------------------------------------------------------
// Fragment order for mfma_f32_16x16x32_bf16 (verified R2/R3):
//   A (MxK): lane l holds m = l&15,  k(j) = 4*(l>>4) + (j&3) + 16*(j>>2)
//   B (KxN): lane l holds n = l&15,  same k(j)
//   D:       lane l holds col = l&15, row = (l>>4)*4 + reg
// 2-term split: z = (x_hi + x_lo) @ W_hi  (absmax ~8e-3 < 2e-2 threshold)
//
// R9: swapped operands -> lane owns (row, 4 cols); aligned pm/out f32x4.
// R10: __launch_bounds__(512,4) is load-bearing.
// R11/12: candidate-compacted Michelot (VALUBusy 33->11%), per-row tau0 seeds.
// R13: phase-overlap. (a) pm rows 0-7 async-staged to LDS via
// global_load_lds BEFORE the GEMM (latency hidden, zero VGPR); gate reads
// LDS for m0<8 lanes, HBM for m0>=8. (b) nontemporal out stores: out is
// never re-read; stop evicting pm from the 256MB L3 between graph replays.
// ---------------------------------------------------------------------------

#define GLOBAL_TO_LDS16(gsrc, ldst)                                          \
    __builtin_amdgcn_global_load_lds(                                        \
        (const __attribute__((address_space(1))) unsigned int*)(gsrc),       \
        (__attribute__((address_space(3))) unsigned int*)(ldst), 16, 0, 0)

__device__ inline void split_bf16(float v, ushort& hi, ushort& lo) {
    __hip_bfloat16 h = __float2bfloat16(v);
    float r = v - __bfloat162float(h);
    __hip_bfloat16 l = __float2bfloat16(r);
    hi = *reinterpret_cast<ushort*>(&h);
    lo = *reinterpret_cast<ushort*>(&l);
}

// W [128][2048] -> Bh[nt=128][kk=4][lane=64][j=8]  (hi only)
__global__ __launch_bounds__(256)
void conv_w_kernel(const float* __restrict__ W, ushort* __restrict__ Bh) {
    int id = blockIdx.x * 256 + threadIdx.x;      // 0 .. 262143
    int j  = id & 7;
    int l  = (id >> 3) & 63;
    int kk = (id >> 9) & 3;
    int nt = id >> 11;
    int k  = kk * 32 + 4 * (l >> 4) + (j & 3) + 16 * (j >> 2);
    int n  = nt * 16 + (l & 15);
    __hip_bfloat16 h = __float2bfloat16(W[k * NDIM + n]);
    Bh[id] = *reinterpret_cast<ushort*>(&h);
}

// x [32768][128] -> A{h,l}[rt=2048][kk=4][lane=64][j=8]
__global__ __launch_bounds__(256)
void conv_x_kernel(const float* __restrict__ x,
                   ushort* __restrict__ Ah, ushort* __restrict__ Al) {
    int id = blockIdx.x * 256 + threadIdx.x;      // 0 .. 4194303
    int j  = id & 7;
    int l  = (id >> 3) & 63;
    int kk = (id >> 9) & 3;
    int rt = id >> 11;
    int k  = kk * 32 + 4 * (l >> 4) + (j & 3) + 16 * (j >> 2);
    int m  = rt * 16 + (l & 15);
    ushort hi, lo;
    split_bf16(x[m * KDIM + k], hi, lo);
    Ah[id] = hi; Al[id] = lo;
}

// ---------------------------------------------------------------------------
// Main: grid 2048, 512 thr (8 waves), 16 rows x 2048 cols per block.
// Wave q: col tiles q*16..q*16+15 (swapped MFMA, acc[16] f32x4 in AGPRs).
// Lane l owns row l&15, cols {q*256 + t*16 + (l>>4)*4 + r}.
// ---------------------------------------------------------------------------
constexpr int GRID  = BATCH / 16;               // 2048
constexpr int CAP   = 128;                      // candidates per row
constexpr int PMPAD = 2052;                     // pm LDS row pitch (2-way-free)
constexpr int PMLDS_BYTES = 8 * PMPAD * 4;      // 65664 B dynamic

__global__ __launch_bounds__(512, 4)
void mfma_sparsemax_swapped(const ushort* __restrict__ Ah, const ushort* __restrict__ Al,
                            const ushort* __restrict__ Bh,
                            const float* __restrict__ pm, float* __restrict__ out) {
    extern __shared__ float pmlds[];            // [8][PMPAD]
    __shared__ float2 red[2][8][16];            // 2 KB
    __shared__ float  cand[16][CAP];            // 8 KB
    __shared__ int    cnt[16];
    __shared__ float  taus0[16];
    __shared__ float  taus[16];

    const int tid = threadIdx.x;
    const int l   = tid & 63;
    const int q   = tid >> 6;                   // wave id 0..7
    const int g   = l >> 4;
    const int m0  = l & 15;                     // my batch row (local)
    const int rt  = blockIdx.x;
    const long grow = (long)rt * 16 + m0;       // my batch row (global)

    const bf16x8* A8h = reinterpret_cast<const bf16x8*>(Ah);
    const bf16x8* A8l = reinterpret_cast<const bf16x8*>(Al);
    const bf16x8* B8h = reinterpret_cast<const bf16x8*>(Bh);

    // ---- async-stage pm rows 0..7 (wave q -> local row q) into LDS ----
    {
        const float* srow = pm + ((long)rt * 16 + q) * NDIM;
        float* drow = pmlds + q * PMPAD;
        #pragma unroll
        for (int chunk = 0; chunk < 8; ++chunk) {
            // lane l: 16B from srow[chunk*256 + l*4] -> drow[chunk*256 + l*4]
            GLOBAL_TO_LDS16(srow + chunk * 256 + l * 4, drow + chunk * 256);
        }
    }

    // ---- x fragments (16 rows of this tile) ----
    bf16x8 ah[4], al4[4];
    #pragma unroll
    for (int kk = 0; kk < 4; ++kk) {
        ah[kk]  = A8h[(rt * 4 + kk) * 64 + l];
        al4[kk] = A8l[(rt * 4 + kk) * 64 + l];
    }

    // ---- GEMM, swapped operands: acc[t] = z[grow][q*256 + t*16 + g*4 .. +3]
    f32x4 acc[16];
    #pragma unroll
    for (int t = 0; t < 16; ++t) {
        const int nt = q * 16 + t;
        f32x4 c = {0.f, 0.f, 0.f, 0.f};
        #pragma unroll
        for (int kk = 0; kk < 4; ++kk) {
            bf16x8 b = B8h[(nt * 4 + kk) * 64 + l];
            c = __builtin_amdgcn_mfma_f32_16x16x32_bf16(b, ah[kk],  c, 0, 0, 0);
            c = __builtin_amdgcn_mfma_f32_16x16x32_bf16(b, al4[kk], c, 0, 0, 0);
        }
        acc[t] = c;
    }

    __syncthreads();                            // [B0] pmlds staged (vmcnt drained)

    // ---- gate by prev_mask: LDS for rows 0-7, HBM for rows 8-15 ----
    if (m0 < 8) {
        const float* myrow = pmlds + m0 * PMPAD + q * 256 + g * 4;
        #pragma unroll
        for (int t = 0; t < 16; ++t)
            acc[t] *= *reinterpret_cast<const f32x4*>(myrow + t * 16);
    } else {
        const float* pmbase = pm + grow * NDIM + q * 256 + g * 4;
        #pragma unroll
        for (int t = 0; t < 16; ++t)
            acc[t] *= *reinterpret_cast<const f32x4*>(pmbase + t * 16);
    }

    // ---- init: row max & sum -> tau0 (per row) ----
    float mx = acc[0][0], sm = 0.f;
    #pragma unroll
    for (int t = 0; t < 16; ++t)
        #pragma unroll
        for (int r = 0; r < 4; ++r) { float v = acc[t][r]; mx = fmaxf(mx, v); sm += v; }
    mx = fmaxf(mx, __shfl_xor(mx, 16, 64));
    mx = fmaxf(mx, __shfl_xor(mx, 32, 64));
    sm += __shfl_xor(sm, 16, 64);
    sm += __shfl_xor(sm, 32, 64);
    if (l < 16) red[0][q][l] = make_float2(mx, sm);
    if (tid < 16) cnt[tid] = 0;
    __syncthreads();                            // [B1]
    float M = -1e30f, S = 0.f;
    #pragma unroll
    for (int w = 0; w < 8; ++w) { float2 e = red[0][w][m0]; M = fmaxf(M, e.x); S += e.y; }
    const float tau0 = fmaxf(M - 1.f, (S - 1.f) * (1.f / 2048.f));
    if (tid < 16) taus0[tid] = tau0;            // tid<16 -> m0 == tid

    // ---- push candidates (v > tau0, own row) into per-row LDS lists ----
    #pragma unroll
    for (int t = 0; t < 16; ++t)
        #pragma unroll
        for (int r = 0; r < 4; ++r) {
            float v = acc[t][r];
            if (v > tau0) {
                int idx = atomicAdd(&cnt[m0], 1);
                if (idx < CAP) cand[m0][idx] = v;
            }
        }
    __syncthreads();                            // [B2]
    const bool ovf = __syncthreads_or((tid < 16) && (cnt[tid] > CAP));  // [B3]

    if (!ovf) {
        // ---- wave-local Michelot: half-wave (q,sub) owns row 2q+sub ----
        const int sub    = l >> 5;
        const int lane32 = l & 31;
        const int row    = 2 * q + sub;
        const int n      = cnt[row];
        const float t0r  = taus0[row];          // THIS row's seed
        float cv[4];
        #pragma unroll
        for (int j = 0; j < 4; ++j) {
            int idx = lane32 + 32 * j;
            cv[j] = (idx < n) ? cand[row][idx] : -1e30f;
        }
        float tau = t0r, cprev = -1.f;
        for (int it = 0; it < 64; ++it) {
            float ps = 0.f, pc = 0.f;
            #pragma unroll
            for (int j = 0; j < 4; ++j) {
                bool a = cv[j] > tau;
                ps += a ? cv[j] : 0.f;
                pc += a ? 1.f : 0.f;
            }
            #pragma unroll
            for (int off = 1; off < 32; off <<= 1) {            // within half-wave
                ps += __shfl_xor(ps, off, 64);
                pc += __shfl_xor(pc, off, 64);
            }
            tau = (ps - 1.f) / pc;              // pc >= 1 (rowmax in candidates)
            bool done = (pc == cprev);
            cprev = pc;
            if (__all(done)) break;
        }
        if (lane32 == 0) taus[row] = tau;
    } else {
        // ---- fallback: block-wide Michelot (degenerate rows) ----
        float tau = tau0, cprev = -1.f;
        for (int it = 0; it < 32; ++it) {
            float ps = 0.f, pc = 0.f;
            #pragma unroll
            for (int t = 0; t < 16; ++t)
                #pragma unroll
                for (int r = 0; r < 4; ++r) {
                    float v = acc[t][r];
                    bool a = v > tau;
                    ps += a ? v : 0.f;
                    pc += a ? 1.f : 0.f;
                }
            ps += __shfl_xor(ps, 16, 64);
            ps += __shfl_xor(ps, 32, 64);
            pc += __shfl_xor(pc, 16, 64);
            pc += __shfl_xor(pc, 32, 64);
            const int buf = (it + 1) & 1;
            if (l < 16) red[buf][q][l] = make_float2(ps, pc);
            __syncthreads();
            float SS = 0.f, CC = 0.f;
            #pragma unroll
            for (int w = 0; w < 8; ++w) { float2 e = red[buf][w][m0]; SS += e.x; CC += e.y; }
            tau = (SS - 1.f) / CC;
            int done = (CC == cprev);
            cprev = CC;
            if (__syncthreads_and(done)) break;
        }
        if (tid < 16) taus[m0] = tau;
    }
    __syncthreads();                            // [B4]
    const float mytau = taus[m0];

    // ---- out = max(z - tau, 0): nontemporal per-lane aligned f32x4 ----
    float* obase = out + grow * NDIM + q * 256 + g * 4;
    #pragma unroll
    for (int t = 0; t < 16; ++t) {
        f32x4 v = acc[t];
        f32x4 o;
        o.x = fmaxf(v.x - mytau, 0.f);
        o.y = fmaxf(v.y - mytau, 0.f);
        o.z = fmaxf(v.z - mytau, 0.f);
        o.w = fmaxf(v.w - mytau, 0.f);
        __builtin_nontemporal_store(o, reinterpret_cast<f32x4*>(obase + t * 16));
    }
}

// ---------------------------------------------------------------------------
// Fallback (R1 kernel) if d_ws too small.
// ---------------------------------------------------------------------------
__device__ inline float wave_sum(float v) {
    #pragma unroll
    for (int off = 32; off > 0; off >>= 1) v += __shfl_xor(v, off, 64);
    return v;
}

__global__ __launch_bounds__(256)
void fused_sparsemax_fallback(const float* __restrict__ x,
                              const float* __restrict__ pm,
                              const float* __restrict__ W,
                              float* __restrict__ out) {
    __shared__ float xs[8][KDIM];
    __shared__ float zsf[4][NDIM];
    const int tid  = threadIdx.x;
    const int lane = tid & 63;
    const int wv   = tid >> 6;
    const long r0  = (long)blockIdx.x * 8;
    {
        const float4* src = reinterpret_cast<const float4*>(x + r0 * KDIM);
        reinterpret_cast<float4*>(&xs[0][0])[tid] = src[tid];
    }
    __syncthreads();
    float acc[8][8];
    #pragma unroll
    for (int r = 0; r < 8; ++r)
        #pragma unroll
        for (int j = 0; j < 8; ++j) acc[r][j] = 0.f;
    const float4* Wv4 = reinterpret_cast<const float4*>(W);
    #pragma unroll 4
    for (int k = 0; k < KDIM; ++k) {
        const float4 w0 = Wv4[k * (NDIM / 4) + tid];
        const float4 w1 = Wv4[k * (NDIM / 4) + 256 + tid];
        #pragma unroll
        for (int r = 0; r < 8; ++r) {
            const float xv = xs[r][k];
            acc[r][0] = fmaf(xv, w0.x, acc[r][0]);
            acc[r][1] = fmaf(xv, w0.y, acc[r][1]);
            acc[r][2] = fmaf(xv, w0.z, acc[r][2]);
            acc[r][3] = fmaf(xv, w0.w, acc[r][3]);
            acc[r][4] = fmaf(xv, w1.x, acc[r][4]);
            acc[r][5] = fmaf(xv, w1.y, acc[r][5]);
            acc[r][6] = fmaf(xv, w1.z, acc[r][6]);
            acc[r][7] = fmaf(xv, w1.w, acc[r][7]);
        }
    }
    const float4* pmv = reinterpret_cast<const float4*>(pm);
    #pragma unroll
    for (int half = 0; half < 2; ++half) {
        __syncthreads();
        #pragma unroll
        for (int rr = 0; rr < 4; ++rr) {
            const int r = half * 4 + rr;
            const long rowbase4 = (r0 + r) * (NDIM / 4);
            const float4 m0 = pmv[rowbase4 + tid];
            const float4 m1 = pmv[rowbase4 + 256 + tid];
            float4 z0, z1;
            z0.x = acc[r][0] * m0.x; z0.y = acc[r][1] * m0.y;
            z0.z = acc[r][2] * m0.z; z0.w = acc[r][3] * m0.w;
            z1.x = acc[r][4] * m1.x; z1.y = acc[r][5] * m1.y;
            z1.z = acc[r][6] * m1.z; z1.w = acc[r][7] * m1.w;
            float4* zr = reinterpret_cast<float4*>(&zsf[rr][0]);
            zr[tid] = z0; zr[256 + tid] = z1;
        }
        __syncthreads();
        float zvv[32];
        const float4* zr = reinterpret_cast<const float4*>(&zsf[wv][0]);
        #pragma unroll
        for (int cc = 0; cc < 8; ++cc) {
            const float4 v = zr[cc * 64 + lane];
            zvv[cc * 4 + 0] = v.x; zvv[cc * 4 + 1] = v.y;
            zvv[cc * 4 + 2] = v.z; zvv[cc * 4 + 3] = v.w;
        }
        float s = 0.f;
        #pragma unroll
        for (int i = 0; i < 32; ++i) s += zvv[i];
        s = wave_sum(s);
        float tau = (s - 1.f) / 2048.f;
        float cprev = 2048.f;
        for (int itf = 0; itf < 64; ++itf) {
            float ps = 0.f, pc = 0.f;
            #pragma unroll
            for (int i = 0; i < 32; ++i)
                if (zvv[i] > tau) { ps += zvv[i]; pc += 1.f; }
            ps = wave_sum(ps);
            pc = wave_sum(pc);
            tau = (ps - 1.f) / pc;
            if (pc == cprev) break;
            cprev = pc;
        }
        float4* orow = reinterpret_cast<float4*>(out + (r0 + half * 4 + wv) * NDIM);
        #pragma unroll
        for (int cc = 0; cc < 8; ++cc) {
            float4 v;
            v.x = fmaxf(zvv[cc * 4 + 0] - tau, 0.f);
            v.y = fmaxf(zvv[cc * 4 + 1] - tau, 0.f);
            v.z = fmaxf(zvv[cc * 4 + 2] - tau, 0.f);
            v.w = fmaxf(zvv[cc * 4 + 3] - tau, 0.f);
            orow[cc * 64 + lane] = v;
        }
    }
}

extern "C" void kernel_launch(void* const* d_in, const int* in_sizes, int n_in,
                              void* d_out, int out_size, void* d_ws, size_t ws_size,
                              hipStream_t stream) {
    const float* x  = (const float*)d_in[0];   // [32768, 128]
    const float* pm = (const float*)d_in[1];   // [32768, 2048]
    const float* W  = (const float*)d_in[2];   // [128, 2048]
    float* out = (float*)d_out;

    const size_t szA = (size_t)BATCH * KDIM * sizeof(ushort);   // 8 MB each
    const size_t szB = (size_t)KDIM * NDIM * sizeof(ushort);    // 512 KB
    const size_t need = 2 * szA + szB;

    if (ws_size >= need) {
        char* base = (char*)d_ws;
        ushort* Ah = (ushort*)(base);
        ushort* Al = (ushort*)(base + szA);
        ushort* Bh = (ushort*)(base + 2 * szA);

        conv_x_kernel<<<(BATCH * KDIM) / 256, 256, 0, stream>>>(x, Ah, Al);
        conv_w_kernel<<<(KDIM * NDIM) / 256, 256, 0, stream>>>(W, Bh);
        mfma_sparsemax_swapped<<<GRID, 512, PMLDS_BYTES, stream>>>(Ah, Al, Bh, pm, out);
    } else {
        fused_sparsemax_fallback<<<BATCH / 8, 256, 0, stream>>>(x, pm, W, out);
    }
}

// Round 14
// 214.410 us; speedup vs baseline: 1.3944x; 1.0292x over previous
//
#include <hip/hip_runtime.h>
#include <hip/hip_bf16.h>

constexpr int BATCH = 32768;
constexpr int KDIM  = 128;    // IN_F
constexpr int NDIM  = 2048;   // OUT_F

using f32x4  = __attribute__((ext_vector_type(4))) float;
using bf16x8 = __attribute__((ext_vector_type(8))) short;

// ---------------------------------------------------------------------------
// Fragment order for mfma_f32_16x16x32_bf16 (verified R2/R3):
//   A (MxK): lane l holds m = l&15,  k(j) = 4*(l>>4) + (j&3) + 16*(j>>2)
//   B (KxN): lane l holds n = l&15,  same k(j)
//   D:       lane l holds col = l&15, row = (l>>4)*4 + reg
// 2-term split: z = (x_hi + x_lo) @ W_hi  (absmax ~8e-3 < 2e-2 threshold)
//
// R14 = R8 (fastest, 210us: z through LDS, wave owns full row) with its three
// measured defects fixed:
//  1) register diet: no zv[32]; sparsemax = 3 LDS re-read passes with pm in
//     32 regs. Peak ~60 arch + 64 AGPR = 124 <= 128 -> 2 blocks/CU (R8: 1).
//  2) PITCH=2056 (mod32=8): scatter 2-way (free), gather conflict-free
//     (R8's PAD=2048: 2.1M conflicts).
//  3) wave-local candidate-compacted Michelot (R12 idea, zero barriers):
//     tau0=max(rowmax-1,(sum-1)/N) in-wave; push C={v>tau0} (<=128) to own
//     LDS list (wave-internal atomics, no sync); 2-reg shuffle solver;
//     per-row full-row fallback if |C|>128.
// NT stores: REVERTED for good (R13: WRITE 262->432MB, pure amplification).
// ---------------------------------------------------------------------------

__device__ inline void split_bf16(float v, ushort& hi, ushort& lo) {
    __hip_bfloat16 h = __float2bfloat16(v);
    float r = v - __bfloat162float(h);
    __hip_bfloat16 l = __float2bfloat16(r);
    hi = *reinterpret_cast<ushort*>(&h);
    lo = *reinterpret_cast<ushort*>(&l);
}

// W [128][2048] -> Bh[nt=128][kk=4][lane=64][j=8]  (hi only)
__global__ __launch_bounds__(256)
void conv_w_kernel(const float* __restrict__ W, ushort* __restrict__ Bh) {
    int id = blockIdx.x * 256 + threadIdx.x;      // 0 .. 262143
    int j  = id & 7;
    int l  = (id >> 3) & 63;
    int kk = (id >> 9) & 3;
    int nt = id >> 11;
    int k  = kk * 32 + 4 * (l >> 4) + (j & 3) + 16 * (j >> 2);
    int n  = nt * 16 + (l & 15);
    __hip_bfloat16 h = __float2bfloat16(W[k * NDIM + n]);
    Bh[id] = *reinterpret_cast<ushort*>(&h);
}

// x [32768][128] -> A{h,l}[rt=2048][kk=4][lane=64][j=8]
__global__ __launch_bounds__(256)
void conv_x_kernel(const float* __restrict__ x,
                   ushort* __restrict__ Ah, ushort* __restrict__ Al) {
    int id = blockIdx.x * 256 + threadIdx.x;      // 0 .. 4194303
    int j  = id & 7;
    int l  = (id >> 3) & 63;
    int kk = (id >> 9) & 3;
    int rt = id >> 11;
    int k  = kk * 32 + 4 * (l >> 4) + (j & 3) + 16 * (j >> 2);
    int m  = rt * 16 + (l & 15);
    ushort hi, lo;
    split_bf16(x[m * KDIM + k], hi, lo);
    Ah[id] = hi; Al[id] = lo;
}

// ---------------------------------------------------------------------------
// Main: grid 2048, 512 thr (8 waves), 16 rows x 2048 cols per block.
// GEMM (normal orientation): wave q -> col tiles q*16+t; acc[t][r] =
//   z[row g*4+r][col q*256+t*16+(l&15)], acc in AGPRs.
// Two 8-row chunks through LDS; wave q owns row (c*8+q): coalesced pm/out,
// wave-local compacted Michelot, no barriers inside the solve.
// ---------------------------------------------------------------------------
constexpr int GRID  = BATCH / 16;               // 2048
constexpr int PITCH = 2056;                     // floats; %32==8
constexpr int CAP   = 128;

__global__ __launch_bounds__(512, 4)
void mfma_sparsemax_kernel(const ushort* __restrict__ Ah, const ushort* __restrict__ Al,
                           const ushort* __restrict__ Bh,
                           const float* __restrict__ pm, float* __restrict__ out) {
    __shared__ float zs[8 * PITCH];             // 65792 B
    __shared__ float cand[8][CAP];              // 4 KB
    __shared__ int   cnt[8];

    const int tid = threadIdx.x;
    const int l   = tid & 63;
    const int q   = tid >> 6;                   // wave id 0..7
    const int g   = l >> 4;
    const int c15 = l & 15;
    const int rt  = blockIdx.x;

    const bf16x8* A8h = reinterpret_cast<const bf16x8*>(Ah);
    const bf16x8* A8l = reinterpret_cast<const bf16x8*>(Al);
    const bf16x8* B8h = reinterpret_cast<const bf16x8*>(Bh);

    // ---- A fragments (16 rows) ----
    bf16x8 ah[4], al4[4];
    #pragma unroll
    for (int kk = 0; kk < 4; ++kk) {
        ah[kk]  = A8h[(rt * 4 + kk) * 64 + l];
        al4[kk] = A8l[(rt * 4 + kk) * 64 + l];
    }

    // ---- GEMM: wave q -> col tiles nt = q*16+t ----
    f32x4 acc[16];
    #pragma unroll
    for (int t = 0; t < 16; ++t) {
        const int nt = q * 16 + t;
        f32x4 c = {0.f, 0.f, 0.f, 0.f};
        #pragma unroll
        for (int kk = 0; kk < 4; ++kk) {
            bf16x8 b = B8h[(nt * 4 + kk) * 64 + l];
            c = __builtin_amdgcn_mfma_f32_16x16x32_bf16(ah[kk],  b, c, 0, 0, 0);
            c = __builtin_amdgcn_mfma_f32_16x16x32_bf16(al4[kk], b, c, 0, 0, 0);
        }
        acc[t] = c;
    }

    // ---- two 8-row chunks through LDS ----
    #pragma unroll
    for (int c = 0; c < 2; ++c) {
        __syncthreads();                        // prev chunk fully consumed

        // scatter: g-groups 2c,2c+1 hold this chunk's rows (local (g&1)*4+r)
        if ((g >> 1) == c) {
            #pragma unroll
            for (int t = 0; t < 16; ++t)
                #pragma unroll
                for (int r = 0; r < 4; ++r)
                    zs[((g & 1) * 4 + r) * PITCH + q * 256 + t * 16 + c15] = acc[t][r];
        }
        if (l == 0) cnt[q] = 0;                 // my row's list count

        // pm prefetch for my row (HBM latency hides under scatter+barrier)
        const long grow = (long)rt * 16 + c * 8 + q;
        const f32x4* pmrow = reinterpret_cast<const f32x4*>(pm + grow * NDIM);
        f32x4 pmv[8];
        #pragma unroll
        for (int j = 0; j < 8; ++j) pmv[j] = pmrow[j * 64 + l];

        __syncthreads();                        // zs ready

        const f32x4* zrow = reinterpret_cast<const f32x4*>(zs + q * PITCH);

        // ---- pass 1: gated row max & sum (wave-wide) ----
        float mx = -1e30f, sm = 0.f;
        #pragma unroll
        for (int j = 0; j < 8; ++j) {
            f32x4 v = zrow[j * 64 + l] * pmv[j];
            mx = fmaxf(mx, fmaxf(fmaxf(v.x, v.y), fmaxf(v.z, v.w)));
            sm += v.x + v.y + v.z + v.w;
        }
        #pragma unroll
        for (int off = 1; off < 64; off <<= 1) {
            mx = fmaxf(mx, __shfl_xor(mx, off, 64));
            sm += __shfl_xor(sm, off, 64);
        }
        const float tau0 = fmaxf(mx - 1.f, (sm - 1.f) * (1.f / 2048.f));

        // ---- pass 2: push candidates (v > tau0) to my row's LDS list ----
        #pragma unroll
        for (int j = 0; j < 8; ++j) {
            f32x4 v = zrow[j * 64 + l] * pmv[j];
            #pragma unroll
            for (int r = 0; r < 4; ++r) {
                float vc = v[r];
                if (vc > tau0) {
                    int idx = atomicAdd(&cnt[q], 1);
                    if (idx < CAP) cand[q][idx] = vc;
                }
            }
        }
        // wave-internal: ds_atomic of all lanes completes before next ds_read
        const int n = cnt[q];

        float tau = tau0;
        if (n <= CAP) {
            // ---- wave-local Michelot on candidates (2 regs/lane) ----
            float cv0 = (l      < n) ? cand[q][l]      : -1e30f;
            float cv1 = (l + 64 < n) ? cand[q][l + 64] : -1e30f;
            float cprev = -1.f;
            for (int it = 0; it < 64; ++it) {
                float ps = 0.f, pc = 0.f;
                if (cv0 > tau) { ps += cv0; pc += 1.f; }
                if (cv1 > tau) { ps += cv1; pc += 1.f; }
                #pragma unroll
                for (int off = 1; off < 64; off <<= 1) {
                    ps += __shfl_xor(ps, off, 64);
                    pc += __shfl_xor(pc, off, 64);
                }
                tau = (ps - 1.f) / pc;          // pc >= 1 (rowmax > tau0)
                if (pc == cprev) break;         // stable count = fixpoint
                cprev = pc;
            }
        } else {
            // ---- rare overflow: full-row Michelot from LDS (wave-local) ----
            float cprev = -1.f;
            for (int it = 0; it < 64; ++it) {
                float ps = 0.f, pc = 0.f;
                #pragma unroll
                for (int j = 0; j < 8; ++j) {
                    f32x4 v = zrow[j * 64 + l] * pmv[j];
                    #pragma unroll
                    for (int r = 0; r < 4; ++r) {
                        if (v[r] > tau) { ps += v[r]; pc += 1.f; }
                    }
                }
                #pragma unroll
                for (int off = 1; off < 64; off <<= 1) {
                    ps += __shfl_xor(ps, off, 64);
                    pc += __shfl_xor(pc, off, 64);
                }
                tau = (ps - 1.f) / pc;
                if (pc == cprev) break;
                cprev = pc;
            }
        }

        // ---- pass 3: out = max(z*pm - tau, 0), coalesced f32x4 ----
        f32x4* orow = reinterpret_cast<f32x4*>(out + grow * NDIM);
        #pragma unroll
        for (int j = 0; j < 8; ++j) {
            f32x4 v = zrow[j * 64 + l] * pmv[j];
            f32x4 o;
            o.x = fmaxf(v.x - tau, 0.f);
            o.y = fmaxf(v.y - tau, 0.f);
            o.z = fmaxf(v.z - tau, 0.f);
            o.w = fmaxf(v.w - tau, 0.f);
            orow[j * 64 + l] = o;
        }
    }
}

// ---------------------------------------------------------------------------
// Fallback (R1 kernel) if d_ws too small.
// ---------------------------------------------------------------------------
__device__ inline float wave_sum(float v) {
    #pragma unroll
    for (int off = 32; off > 0; off >>= 1) v += __shfl_xor(v, off, 64);
    return v;
}

__global__ __launch_bounds__(256)
void fused_sparsemax_fallback(const float* __restrict__ x,
                              const float* __restrict__ pm,
                              const float* __restrict__ W,
                              float* __restrict__ out) {
    __shared__ float xs[8][KDIM];
    __shared__ float zsf[4][NDIM];
    const int tid  = threadIdx.x;
    const int lane = tid & 63;
    const int wv   = tid >> 6;
    const long r0  = (long)blockIdx.x * 8;
    {
        const float4* src = reinterpret_cast<const float4*>(x + r0 * KDIM);
        reinterpret_cast<float4*>(&xs[0][0])[tid] = src[tid];
    }
    __syncthreads();
    float acc[8][8];
    #pragma unroll
    for (int r = 0; r < 8; ++r)
        #pragma unroll
        for (int j = 0; j < 8; ++j) acc[r][j] = 0.f;
    const float4* Wv4 = reinterpret_cast<const float4*>(W);
    #pragma unroll 4
    for (int k = 0; k < KDIM; ++k) {
        const float4 w0 = Wv4[k * (NDIM / 4) + tid];
        const float4 w1 = Wv4[k * (NDIM / 4) + 256 + tid];
        #pragma unroll
        for (int r = 0; r < 8; ++r) {
            const float xv = xs[r][k];
            acc[r][0] = fmaf(xv, w0.x, acc[r][0]);
            acc[r][1] = fmaf(xv, w0.y, acc[r][1]);
            acc[r][2] = fmaf(xv, w0.z, acc[r][2]);
            acc[r][3] = fmaf(xv, w0.w, acc[r][3]);
            acc[r][4] = fmaf(xv, w1.x, acc[r][4]);
            acc[r][5] = fmaf(xv, w1.y, acc[r][5]);
            acc[r][6] = fmaf(xv, w1.z, acc[r][6]);
            acc[r][7] = fmaf(xv, w1.w, acc[r][7]);
        }
    }
    const float4* pmv = reinterpret_cast<const float4*>(pm);
    #pragma unroll
    for (int half = 0; half < 2; ++half) {
        __syncthreads();
        #pragma unroll
        for (int rr = 0; rr < 4; ++rr) {
            const int r = half * 4 + rr;
            const long rowbase4 = (r0 + r) * (NDIM / 4);
            const float4 m0 = pmv[rowbase4 + tid];
            const float4 m1 = pmv[rowbase4 + 256 + tid];
            float4 z0, z1;
            z0.x = acc[r][0] * m0.x; z0.y = acc[r][1] * m0.y;
            z0.z = acc[r][2] * m0.z; z0.w = acc[r][3] * m0.w;
            z1.x = acc[r][4] * m1.x; z1.y = acc[r][5] * m1.y;
            z1.z = acc[r][6] * m1.z; z1.w = acc[r][7] * m1.w;
            float4* zr = reinterpret_cast<float4*>(&zsf[rr][0]);
            zr[tid] = z0; zr[256 + tid] = z1;
        }
        __syncthreads();
        float zvv[32];
        const float4* zr = reinterpret_cast<const float4*>(&zsf[wv][0]);
        #pragma unroll
        for (int cc = 0; cc < 8; ++cc) {
            const float4 v = zr[cc * 64 + lane];
            zvv[cc * 4 + 0] = v.x; zvv[cc * 4 + 1] = v.y;
            zvv[cc * 4 + 2] = v.z; zvv[cc * 4 + 3] = v.w;
        }
        float s = 0.f;
        #pragma unroll
        for (int i = 0; i < 32; ++i) s += zvv[i];
        s = wave_sum(s);
        float tau = (s - 1.f) / 2048.f;
        float cprev = 2048.f;
        for (int itf = 0; itf < 64; ++itf) {
            float ps = 0.f, pc = 0.f;
            #pragma unroll
            for (int i = 0; i < 32; ++i)
                if (zvv[i] > tau) { ps += zvv[i]; pc += 1.f; }
            ps = wave_sum(ps);
            pc = wave_sum(pc);
            tau = (ps - 1.f) / pc;
            if (pc == cprev) break;
            cprev = pc;
        }
        float4* orow = reinterpret_cast<float4*>(out + (r0 + half * 4 + wv) * NDIM);
        #pragma unroll
        for (int cc = 0; cc < 8; ++cc) {
            float4 v;
            v.x = fmaxf(zvv[cc * 4 + 0] - tau, 0.f);
            v.y = fmaxf(zvv[cc * 4 + 1] - tau, 0.f);
            v.z = fmaxf(zvv[cc * 4 + 2] - tau, 0.f);
            v.w = fmaxf(zvv[cc * 4 + 3] - tau, 0.f);
            orow[cc * 64 + lane] = v;
        }
    }
}

extern "C" void kernel_launch(void* const* d_in, const int* in_sizes, int n_in,
                              void* d_out, int out_size, void* d_ws, size_t ws_size,
                              hipStream_t stream) {
    const float* x  = (const float*)d_in[0];   // [32768, 128]
    const float* pm = (const float*)d_in[1];   // [32768, 2048]
    const float* W  = (const float*)d_in[2];   // [128, 2048]
    float* out = (float*)d_out;

    const size_t szA = (size_t)BATCH * KDIM * sizeof(ushort);   // 8 MB each
    const size_t szB = (size_t)KDIM * NDIM * sizeof(ushort);    // 512 KB
    const size_t need = 2 * szA + szB;

    if (ws_size >= need) {
        char* base = (char*)d_ws;
        ushort* Ah = (ushort*)(base);
        ushort* Al = (ushort*)(base + szA);
        ushort* Bh = (ushort*)(base + 2 * szA);

        conv_x_kernel<<<(BATCH * KDIM) / 256, 256, 0, stream>>>(x, Ah, Al);
        conv_w_kernel<<<(KDIM * NDIM) / 256, 256, 0, stream>>>(W, Bh);
        mfma_sparsemax_kernel<<<GRID, 512, 0, stream>>>(Ah, Al, Bh, pm, out);
    } else {
        fused_sparsemax_fallback<<<BATCH / 8, 256, 0, stream>>>(x, pm, W, out);
    }
}